// Round 7
// baseline (11503.705 us; speedup 1.0000x reference)
//
#include <hip/hip_runtime.h>

// ============================================================================
// Tatt: temp construction (analytic roll-collapse) -> 3x gated GCN (fused-pair
// f16 MFMA GEMM N=768 + banded A-mul + tanh*sigmoid) -> Conv1d(k=577) as
// implicit-im2col f16 MFMA GEMM (split-K=7, atomic reduce) -> bias+transpose.
//
// Dims: B=32, T1=288, T3=864, N=H=325 (pad K->352 "IPAD", pad N->384 "NPAD"),
// KSIZE=577. Conv GEMM: M=9216, N=384(pad), Kflat=577*352=203104 (pad 203136).
//
// R7: k_conv cross-chunk register double-buffer. R4-R6 were additive
// (MFMA 1863 + LDS 1700 cyc/chunk = 3546 observed) because MFMA(k) was
// data-dependent on ds_reads(k) in the same barrier window -> CU globally
// alternates LDS-phase / MFMA-phase. Now: frags(k+1) are ds_read into a
// SECOND register set during MFMA(k) (operands of MFMA(k) already in regs,
// no lgkm gate between) -> LDS pipe drains under the matrix pipe.
// Invariants: per chunk {stage(k+2); vmcnt(5)=k+1 landed; lgkmcnt(0) BEFORE
// barrier (2-barrier separation between slot reads and slot re-write);
// barrier; body = 14 ds_reads(k+1) + 48 MFMA(k)}. Unroll x2 for static
// frag ping-pong (rule #20); odd tail chunk separate.
// ============================================================================

typedef _Float16 half8 __attribute__((ext_vector_type(8)));
typedef float floatx4 __attribute__((ext_vector_type(4)));

#define DEV __device__ __forceinline__
#define AS1 __attribute__((address_space(1)))
#define AS3 __attribute__((address_space(3)))

constexpr int IPAD = 352;                 // padded inner (sensor) dim
constexpr int NPAD = 384;                 // padded outer (channel) dim
constexpr int NFUSE = 768;                // fused GCN output (two gates)
constexpr int MGCN = 32 * 864;            // 27648
constexpr int MCONV = 32 * 288;           // 9216
constexpr int KCONV_PAD = 203136;         // 3174 * 64  (>= 577*352 = 203104)
constexpr int CONV_SPLITS = 7;
constexpr int CH32_TOTAL = KCONV_PAD / 32;           // 6348
constexpr int CH32_PER = 907;                        // ceil(6348/7); last split 906

// ---- workspace layout (bytes) ----
constexpr size_t OFF_XG = 0;                                   // f16 [27649][352]
constexpr size_t SZ_XG_AL = 19465216;                          // 27649*352*2, aligned
constexpr size_t OFF_S = OFF_XG + SZ_XG_AL;                    // f32 [27648][768] fused
constexpr size_t SZ_S = (size_t)MGCN * NFUSE * 4;              // 84934656
constexpr size_t OFF_WG = OFF_S + SZ_S;                        // 6 * [384][384] f16
constexpr size_t SZ_WG = 6ull * NPAD * NPAD * 2;               // 1769472
constexpr size_t OFF_WCONV = OFF_WG + SZ_WG;                   // [384][203136] f16
constexpr size_t OFF_CPART = OFF_S;                            // alias: f32 [9216][384]
// total = OFF_WCONV + 384*203136*2 = 262,177,792 bytes

DEV void gload16(const void* g, void* l) {
    __builtin_amdgcn_global_load_lds((const AS1 void*)g, (AS3 void*)l, 16, 0, 0);
}

#define MEMFENCE() asm volatile("" ::: "memory")
#define BARRIER() do { MEMFENCE(); __builtin_amdgcn_s_barrier(); MEMFENCE(); } while (0)
#define MFMA16(a, b, c) __builtin_amdgcn_mfma_f32_16x16x32_f16((a), (b), (c), 0, 0, 0)

// ---------------------------------------------------------------------------
// temp:  Xg[b*864+m][i] = (m in [288,576)) ? IF[b][i][m-288]
//                        : x[(m + s_b + 1728) % 2016][i],   0 for i>=325
// ---------------------------------------------------------------------------
__global__ void k_temp(const float* __restrict__ IF, const float* __restrict__ x,
                       const int* __restrict__ week, const int* __restrict__ hour,
                       _Float16* __restrict__ Xg) {
    int idx = blockIdx.x * 256 + threadIdx.x;       // over 27648*352
    if (idx >= MGCN * IPAD) return;
    int i  = idx % IPAD;
    int mm = idx / IPAD;
    int m  = mm % 864, b = mm / 864;
    float v = 0.f;
    if (i < 325) {
        if (m >= 288 && m < 576) {
            v = IF[((size_t)b * 325 + i) * 288 + (m - 288)];
        } else {
            int s  = week[b] * 288 + hour[b];
            int tm = (m + s + 1728) % 2016;
            v = x[(size_t)tm * 325 + i];
        }
    }
    Xg[(size_t)mm * IPAD + i] = (_Float16)v;
}

// ---------------------------------------------------------------------------
// pack 6 GCN weights, transposed + zero-padded:  Wg[l][o][d] = w_l[d*325+o]
// (pairs 2l,2l+1 are contiguous -> fused GEMM sees one [768][384] B panel)
// ---------------------------------------------------------------------------
__global__ void k_pack_gcn(const float* w0, const float* w1, const float* w2,
                           const float* w3, const float* w4, const float* w5,
                           _Float16* __restrict__ Wg) {
    int idx = blockIdx.x * 256 + threadIdx.x;       // 6*384*384
    int d = idx % NPAD;
    int o = (idx / NPAD) % NPAD;
    int l = idx / (NPAD * NPAD);
    const float* w = l == 0 ? w0 : l == 1 ? w1 : l == 2 ? w2 : l == 3 ? w3 : l == 4 ? w4 : w5;
    float v = (o < 325 && d < 325) ? w[d * 325 + o] : 0.f;
    Wg[(size_t)idx] = (_Float16)v;
}

// ---------------------------------------------------------------------------
// pack conv weights:  Wc[o][k*352+i] = conv_w[o][i][k]  (zero-padded)
// ---------------------------------------------------------------------------
__global__ void k_pack_conv(const float* __restrict__ cw, _Float16* __restrict__ Wc) {
    __shared__ float tile[32][33];
    int o = blockIdx.x, i0 = blockIdx.y * 32, k0 = blockIdx.z * 32;
    int t = threadIdx.x;
    int c = t & 31, r4 = t >> 5;
#pragma unroll
    for (int p = 0; p < 4; ++p) {
        int ii = r4 * 4 + p;
        int i = i0 + ii, k = k0 + c;
        float v = 0.f;
        if (o < 325 && i < 325 && k < 577) v = cw[((size_t)o * 325 + i) * 577 + k];
        tile[ii][c] = v;
    }
    __syncthreads();
#pragma unroll
    for (int p = 0; p < 4; ++p) {
        int kk = r4 * 4 + p;
        int k = k0 + kk, i = i0 + c;
        int kidx = k * IPAD + i;
        if (kidx < KCONV_PAD) Wc[(size_t)o * KCONV_PAD + kidx] = (_Float16)tile[c][kk];
    }
}

// ---------------------------------------------------------------------------
// fused GCN GEMM: 128x128 tile over [27648][768], BK=64 x 6 chunks (K padded
// 384; zero-padded tails contribute 0). global_load_lds + XOR swizzle.
// C[m][n] = sum_K A[m][K] * Bw[n][K], C stride = 768.
// ---------------------------------------------------------------------------
__global__ __launch_bounds__(256) void k_gemm(const _Float16* __restrict__ Xg,
                                              const _Float16* __restrict__ Bw,
                                              float* __restrict__ C) {
    __shared__ _Float16 sA[128 * 64];
    __shared__ _Float16 sB[128 * 64];
    const int t = threadIdx.x;
    const int m0 = blockIdx.x * 128, n0 = blockIdx.y * 128;

    const int rj = t >> 3;
    const int cg = (t & 7) ^ (rj & 7);
    const _Float16* pa[4];
    const _Float16* pb[4];
#pragma unroll
    for (int j = 0; j < 4; ++j) {
        int m = m0 + j * 32 + rj;
        pa[j] = Xg + (size_t)m * IPAD + cg * 8;
        int n = n0 + j * 32 + rj;
        pb[j] = Bw + (size_t)n * NPAD + cg * 8;
    }

    const int lane = t & 63, wv = t >> 6;
    const int wm = wv >> 1, wn = wv & 1;            // 2x2 waves of 64x64
    const int r = lane & 15, q = lane >> 4, s8 = r & 7;
    int aRow[4], bRow[4];
#pragma unroll
    for (int i = 0; i < 4; ++i) {
        aRow[i] = (wm * 64 + i * 16 + r) * 64;
        bRow[i] = (wn * 64 + i * 16 + r) * 64;
    }
    const int xk0 = (q ^ s8) * 8;
    const int xk1 = ((q + 4) ^ s8) * 8;

    floatx4 acc[4][4] = {};

    for (int ch = 0; ch < 6; ++ch) {
        __syncthreads();
#pragma unroll
        for (int j = 0; j < 4; ++j) { gload16(pa[j], &sA[(j * 256 + t) * 8]); pa[j] += 64; }
#pragma unroll
        for (int j = 0; j < 4; ++j) { gload16(pb[j], &sB[(j * 256 + t) * 8]); pb[j] += 64; }
        __syncthreads();
#pragma unroll
        for (int kk = 0; kk < 2; ++kk) {
            const int xk = kk ? xk1 : xk0;
            half8 av[4], bv[4];
#pragma unroll
            for (int mi = 0; mi < 4; ++mi) av[mi] = *(const half8*)(sA + aRow[mi] + xk);
#pragma unroll
            for (int ni = 0; ni < 4; ++ni) bv[ni] = *(const half8*)(sB + bRow[ni] + xk);
#pragma unroll
            for (int mi = 0; mi < 4; ++mi)
#pragma unroll
                for (int ni = 0; ni < 4; ++ni)
                    acc[mi][ni] = MFMA16(av[mi], bv[ni], acc[mi][ni]);
        }
    }

    // C/D layout: col = lane&15, row = (lane>>4)*4 + reg   [m89-verified]
#pragma unroll
    for (int mi = 0; mi < 4; ++mi)
#pragma unroll
        for (int ni = 0; ni < 4; ++ni) {
            int row = m0 + wm * 64 + mi * 16 + q * 4;
            int col = n0 + wn * 64 + ni * 16 + r;
#pragma unroll
            for (int e = 0; e < 4; ++e)
                C[(size_t)(row + e) * NFUSE + col] = acc[mi][ni][e];
        }
}

// ---------------------------------------------------------------------------
// conv GEMM: 256x384 tile (full N), BK=32, 512 threads = 8 waves, 2M x 4N
// (wave tile 128x96). Triple-buffered LDS (3 x 40 KB), depth-2 global
// prefetch, cross-chunk REGISTER double-buffer: body of chunk k = 14
// ds_reads of chunk k+1 frags (into the other reg set) + 48 MFMA of chunk k
// (operands already in regs -> no lgkm gate; LDS pipe overlaps matrix pipe).
// Per chunk: stage(k+2); vmcnt(5) [k+1 landed]; lgkmcnt(0) BEFORE barrier
// [reads of a slot are 2 barriers ahead of its re-write]; barrier; body.
// Split-K=7 (252 blocks); partials via HW f32 atomics into zeroed buffer.
//
// LDS layout per buffer: A = 128 "pair-lines" (rows 2j,2j+1; 8 x 16B blocks,
// 128 B/line) then B = 192 pair-lines. Slot (j,cc) holds global block
// g = cc ^ (j&7), g = (rowparity<<2)|kblk. Frag reads: stepping 16 rows = 8
// lines keeps (row>>1)&7 -> offset = base + idx*1024; 2-way bank aliasing
// max (free, m136). LDS dest is wave-uniform base + lane*16 (m104-safe).
// ---------------------------------------------------------------------------
__global__ __launch_bounds__(512, 2) void k_conv(const _Float16* __restrict__ Xg,
                                                 const _Float16* __restrict__ Wc,
                                                 float* __restrict__ C) {
    __shared__ _Float16 lds[3 * 20480];             // 3 x 40960 B = 122880 B
    const int t = threadIdx.x;
    const int m0 = blockIdx.x * 256;
    const int chunk0 = blockIdx.y * CH32_PER;
    int nch = CH32_TOTAL - chunk0;
    if (nch > CH32_PER) nch = CH32_PER;             // last split: 906

    // ---- staging: 5 slots/thread (2 A + 3 B) ----
    const _Float16* src[5];
    int ldsoff[5];                                  // byte offset within a buffer
#pragma unroll
    for (int p = 0; p < 2; ++p) {
        int s = t + p * 512;                        // A slot 0..1023
        int j = s >> 3, cc = s & 7;
        int g = cc ^ (j & 7);
        int m = m0 + 2 * j + (g >> 2);
        int mrow = m + (m / 288) * 576;             // implicit im2col
        src[p] = Xg + (size_t)mrow * IPAD + (size_t)chunk0 * 32 + (g & 3) * 8;
        ldsoff[p] = s * 16;
    }
#pragma unroll
    for (int p = 0; p < 3; ++p) {
        int s = t + p * 512;                        // B slot 0..1535
        int j = s >> 3, cc = s & 7;
        int g = cc ^ (j & 7);
        int n = 2 * j + (g >> 2);
        src[2 + p] = Wc + (size_t)n * KCONV_PAD + (size_t)chunk0 * 32 + (g & 3) * 8;
        ldsoff[2 + p] = 16384 + s * 16;
    }

    // ---- fragment read offsets (2M x 4N) ----
    const int lane = t & 63, wv = t >> 6;
    const int wm = wv >> 2, wn = wv & 3;
    const int r = lane & 15, q = lane >> 4;
    int row_a = wm * 128 + r;
    int aoff0 = (row_a >> 1) * 128 + ((((row_a & 1) << 2) | q) ^ ((row_a >> 1) & 7)) * 16;
    int row_b = wn * 96 + r;
    int boff0 = 16384 + (row_b >> 1) * 128 +
                ((((row_b & 1) << 2) | q) ^ ((row_b >> 1) & 7)) * 16;

    floatx4 acc[8][6] = {};
    half8 fA[8], gA[6];                             // fragment reg buffer A
    half8 fB[8], gB[6];                             // fragment reg buffer B

    auto stage = [&](int lc, int buf) {
        char* dst = (char*)lds + buf * 40960;
        size_t adv = (size_t)lc * 32;               // 32 halfs = 64 B per chunk
#pragma unroll
        for (int p = 0; p < 5; ++p)
            gload16(src[p] + adv, dst + ldsoff[p]);
    };

#define READ_FRAGS(cbp, av, bv)                                        \
    do {                                                               \
        _Pragma("unroll")                                              \
        for (int ni = 0; ni < 6; ++ni)                                 \
            (bv)[ni] = *(const half8*)((cbp) + boff0 + ni * 1024);     \
        _Pragma("unroll")                                              \
        for (int mi = 0; mi < 8; ++mi)                                 \
            (av)[mi] = *(const half8*)((cbp) + aoff0 + mi * 1024);     \
    } while (0)

#define MFMA_ALL(av, bv)                                               \
    do {                                                               \
        __builtin_amdgcn_s_setprio(1);                                 \
        _Pragma("unroll")                                              \
        for (int mi = 0; mi < 8; ++mi)                                 \
            _Pragma("unroll")                                          \
            for (int ni = 0; ni < 6; ++ni)                             \
                acc[mi][ni] = MFMA16((av)[mi], (bv)[ni], acc[mi][ni]); \
        __builtin_amdgcn_s_setprio(0);                                 \
    } while (0)

    // prologue: chunks 0,1 staged; read chunk-0 frags into buffer A
    stage(0, 0);
    stage(1, 1);
    asm volatile("s_waitcnt vmcnt(5)" ::: "memory");   // chunk 0 landed
    BARRIER();
    READ_FRAGS((const char*)lds, fA, gA);

    int k = 0;
    for (; k + 1 < nch; k += 2) {
        // --- iter A: MFMA chunk k (A-regs) || read chunk k+1 -> B-regs ---
        {
            int pre = k + 2; if (pre > nch - 1) pre = nch - 1;
            int sl = k + 2; sl -= (sl / 3) * 3;
            stage(pre, sl);
            asm volatile("s_waitcnt vmcnt(5)" ::: "memory");    // chunk k+1 landed
            asm volatile("s_waitcnt lgkmcnt(0)" ::: "memory");  // prior frag reads drained
            BARRIER();
            int rs = k + 1; rs -= (rs / 3) * 3;
            const char* cb = (const char*)lds + rs * 40960;
            READ_FRAGS(cb, fB, gB);                  // no wait: MFMA below uses A-regs
            MFMA_ALL(fA, gA);
        }
        // --- iter B: MFMA chunk k+1 (B-regs) || read chunk k+2 -> A-regs ---
        {
            int pre = k + 3; if (pre > nch - 1) pre = nch - 1;
            int sl = k + 3; sl -= (sl / 3) * 3;
            stage(pre, sl);
            asm volatile("s_waitcnt vmcnt(5)" ::: "memory");    // chunk k+2 landed
            asm volatile("s_waitcnt lgkmcnt(0)" ::: "memory");
            BARRIER();
            int rs = k + 2; rs -= (rs / 3) * 3;
            const char* cb = (const char*)lds + rs * 40960;
            READ_FRAGS(cb, fA, gA);                  // garbage if k+2>=nch (never used)
            MFMA_ALL(fB, gB);
        }
    }
    if (k < nch) {                                   // odd tail: chunk nch-1 in A-regs
        asm volatile("s_waitcnt lgkmcnt(0)" ::: "memory");
        __builtin_amdgcn_sched_barrier(0);
        MFMA_ALL(fA, gA);
    }
    asm volatile("s_waitcnt vmcnt(0)" ::: "memory");

    // C/D layout: col = lane&15, row = (lane>>4)*4 + reg   [m89-verified]
    // HW f32 atomic add (unsafeAtomicAdd -> global_atomic_add_f32)
#pragma unroll
    for (int mi = 0; mi < 8; ++mi)
#pragma unroll
        for (int ni = 0; ni < 6; ++ni) {
            int row = m0 + wm * 128 + mi * 16 + q * 4;
            int col = wn * 96 + ni * 16 + r;
#pragma unroll
            for (int e = 0; e < 4; ++e)
                unsafeAtomicAdd(&C[(size_t)(row + e) * NPAD + col], acc[mi][ni][e]);
        }
#undef READ_FRAGS
#undef MFMA_ALL
}

// ---------------------------------------------------------------------------
// banded D^-1/2 A D^-1/2 (7-diag) + bias + tanh*sigmoid -> f16 Xg (in place)
// Fused S layout: S[m][0..383] = gate1 (tanh), S[m][384..767] = gate2 (sigm).
// ---------------------------------------------------------------------------
__global__ void k_bandact(const float* __restrict__ S,
                          const float* __restrict__ b1, const float* __restrict__ b2,
                          _Float16* __restrict__ Xg) {
    int bm = blockIdx.x;                            // 0..27647
    int m = bm % 864;
    int dm = (m < 3 ? m : 3) + ((863 - m) < 3 ? (863 - m) : 3) + 1;
    for (int o = threadIdx.x; o < 325; o += 256) {
        float g1 = b1[o], g2 = b2[o];
#pragma unroll
        for (int dn = -3; dn <= 3; ++dn) {
            int n = m + dn;
            if (n < 0 || n > 863) continue;
            int dnd = (n < 3 ? n : 3) + ((863 - n) < 3 ? (863 - n) : 3) + 1;
            float a = rsqrtf((float)(dm * dnd));
            size_t off = (size_t)(bm + dn) * NFUSE + o;
            g1 += a * S[off];
            g2 += a * S[off + NPAD];
        }
        float vt = tanhf(g1);
        float vs = 1.f / (1.f + expf(-g2));
        Xg[(size_t)bm * IPAD + o] = (_Float16)(vt * vs);
    }
}

// ---------------------------------------------------------------------------
// conv bias + transpose [m=(b,t)][o] -> out[b][o][t]
// ---------------------------------------------------------------------------
__global__ void k_reduce(const float* __restrict__ Cp, const float* __restrict__ cb,
                         float* __restrict__ out) {
    __shared__ float tile[32][33];
    int b = blockIdx.x, t0 = blockIdx.y * 32, o0 = blockIdx.z * 32;
    int t = threadIdx.x;
    int c = t & 31, r4 = t >> 5;
#pragma unroll
    for (int p = 0; p < 4; ++p) {
        int tt = r4 * 4 + p;
        tile[tt][c] = Cp[(size_t)(b * 288 + t0 + tt) * NPAD + (o0 + c)];
    }
    __syncthreads();
#pragma unroll
    for (int p = 0; p < 4; ++p) {
        int oo = r4 * 4 + p;
        int o = o0 + oo;
        if (o < 325)
            out[((size_t)b * 325 + o) * 288 + t0 + c] = tile[c][oo] + cb[o];
    }
}

// ---------------------------------------------------------------------------
extern "C" void kernel_launch(void* const* d_in, const int* in_sizes, int n_in,
                              void* d_out, int out_size, void* d_ws, size_t ws_size,
                              hipStream_t stream) {
    const float* IF = (const float*)d_in[0];
    const float* x  = (const float*)d_in[1];
    const float* wg[6] = {(const float*)d_in[2],  (const float*)d_in[4],
                          (const float*)d_in[6],  (const float*)d_in[8],
                          (const float*)d_in[10], (const float*)d_in[12]};
    const float* bg[6] = {(const float*)d_in[3],  (const float*)d_in[5],
                          (const float*)d_in[7],  (const float*)d_in[9],
                          (const float*)d_in[11], (const float*)d_in[13]};
    const float* cw  = (const float*)d_in[14];
    const float* cb  = (const float*)d_in[15];
    const int* week  = (const int*)d_in[16];
    const int* hour  = (const int*)d_in[17];
    float* out = (float*)d_out;

    char* ws = (char*)d_ws;
    _Float16* Xg = (_Float16*)(ws + OFF_XG);
    float* S     = (float*)(ws + OFF_S);
    _Float16* Wg = (_Float16*)(ws + OFF_WG);
    _Float16* Wc = (_Float16*)(ws + OFF_WCONV);
    float* Cp    = (float*)(ws + OFF_CPART);   // aliases S (conv phase only)

    k_pack_gcn<<<(6 * NPAD * NPAD) / 256, 256, 0, stream>>>(wg[0], wg[1], wg[2], wg[3],
                                                            wg[4], wg[5], Wg);
    k_pack_conv<<<dim3(NPAD, 11, 19), 256, 0, stream>>>(cw, Wc);
    k_temp<<<(MGCN * IPAD) / 256, 256, 0, stream>>>(IF, x, week, hour, Xg);

    for (int l = 0; l < 3; ++l) {
        k_gemm<<<dim3(MGCN / 128, NFUSE / 128), 256, 0, stream>>>(
            Xg, Wg + (size_t)(2 * l) * NPAD * NPAD, S);
        k_bandact<<<MGCN, 256, 0, stream>>>(S, bg[2 * l], bg[2 * l + 1], Xg);
    }

    hipMemsetAsync(Cp, 0, (size_t)MCONV * NPAD * 4, stream);
    k_conv<<<dim3(MCONV / 256, CONV_SPLITS), 512, 0, stream>>>(Xg, Wc, Cp);

    k_reduce<<<dim3(32, 9, 11), 256, 0, stream>>>(Cp, cb, out);
}